// Round 1
// baseline (259.790 us; speedup 1.0000x reference)
//
#include <hip/hip_runtime.h>
#include <hip/hip_bf16.h>

#define BATCH 16
#define HH    48
#define WW    64
#define CC    256
#define ND    21          // displacements per axis
#define OUTD  441         // 21*21
#define PITCH 264         // LDS row pitch in bf16 elems (256 + 8): 16B-aligned rows, 4-bank shift/row
#define BROWS 52          // per-parity B rows: s = j' + 10, j' in [-10, 42)

typedef __bf16 v8bf16 __attribute__((ext_vector_type(8)));
typedef float  v4f    __attribute__((ext_vector_type(4)));

// out[b,h,w, tj*21+ti] = (1/256) * sum_c A[b,h,w,c] * Bpad[b, h+2tj-20, w+2ti-20, c]
// Parity split: w = 2w'+p, j = w+2ti-20 = 2(w'+ti-10)+p -> j' = w'+ti-10, ti = s - w' with s = j'+10.
__global__ __launch_bounds__(256)
void corr_mfma_kernel(const float* __restrict__ A, const float* __restrict__ B,
                      float* __restrict__ out) {
    // B row staged by parity: Blds[p][s][c], s in [0,52); rows s<10 or s>=42 stay zero (spatial pad)
    __shared__ __bf16 Blds[2 * BROWS * PITCH];   // 54,912 B

    const int bh   = blockIdx.x;
    const int b    = bh / HH;
    const int h    = bh % HH;
    const int tid  = threadIdx.x;
    const int lane = tid & 63;
    const int wave = tid >> 6;
    const int p    = wave & 1;    // parity of w
    const int mt   = wave >> 1;   // w'-tile: m0 = 16*mt
    const int n    = lane & 15;
    const int quad = lane >> 4;

    float* outbh = out + (size_t)(b * HH + h) * WW * OUTD;

    // valid tj range: hb = h + 2*tj - 20 in [0,48)
    const int tj_lo = (h >= 20) ? 0 : ((21 - h) >> 1);
    const int tj_hi = min(20, (67 - h) >> 1);

    // zero-fill outputs for invalid tj (B row fully out of range)
    for (int tj = 0; tj < ND; ++tj) {
        if (tj >= tj_lo && tj <= tj_hi) continue;
        for (int idx = tid; idx < WW * ND; idx += 256) {
            int w = idx / ND, ti = idx - w * ND;
            outbh[(size_t)w * OUTD + tj * ND + ti] = 0.f;
        }
    }

    // zero the border rows of Blds once (they encode the spatial zero-padding)
    // 40 rows (per parity: s in [0,10) U [42,52)) x 256 c -> 2560 chunks of 4 bf16
    #pragma unroll
    for (int it = 0; it < 10; ++it) {
        int chunk = it * 256 + tid;          // [0, 2560)
        int row   = chunk >> 6;              // [0, 40)
        int c4    = (chunk & 63) << 2;
        int pp    = (row >= 20) ? 1 : 0;
        int sz    = row - pp * 20;
        int s     = (sz < 10) ? sz : (sz + 32);
        __bf16* dst = &Blds[(pp * BROWS + s) * PITCH + c4];
        *(uint2*)dst = make_uint2(0u, 0u);   // 4 zero bf16
    }

    // Preload A fragments (tj-invariant): lane holds A_p[m0+n][kc*32 + quad*8 .. +7]
    v8bf16 afrag[8];
    {
        int w_a = ((mt * 16 + n) << 1) + p;
        const float* arow = A + ((size_t)(b * HH + h) * WW + w_a) * CC;
        #pragma unroll
        for (int kc = 0; kc < 8; ++kc) {
            int c0 = kc * 32 + quad * 8;
            float4 f0 = *(const float4*)(arow + c0);
            float4 f1 = *(const float4*)(arow + c0 + 4);
            v8bf16 af;
            af[0] = (__bf16)f0.x; af[1] = (__bf16)f0.y; af[2] = (__bf16)f0.z; af[3] = (__bf16)f0.w;
            af[4] = (__bf16)f1.x; af[5] = (__bf16)f1.y; af[6] = (__bf16)f1.z; af[7] = (__bf16)f1.w;
            afrag[kc] = af;
        }
    }

    // j'-tile bases (in s coords). mt=0 needs s[0,36): tiles {0,16,32}.
    // mt=1 needs s[16,52): tiles {6,20,36} (tile0 write-restricted to n<14 to dedup overlap [20,22))
    const int s0_0 = mt ? 6  : 0;
    const int s0_1 = mt ? 20 : 16;
    const int s0_2 = mt ? 36 : 32;

    for (int tj = tj_lo; tj <= tj_hi; ++tj) {
        const int hb = h + 2 * tj - 20;
        __syncthreads();   // previous compute done before overwriting Blds

        // stage B[b, hb, :, :] -> Blds (valid rows s in [10,42)); 4096 chunks of 4 floats
        const float* brow = B + (size_t)(b * HH + hb) * WW * CC;
        #pragma unroll
        for (int it = 0; it < 16; ++it) {
            int chunk = it * 256 + tid;      // [0, 4096)
            int w  = chunk >> 6;             // [0, 64) — one w per wave-iter (coalesced)
            int c4 = (chunk & 63) << 2;
            float4 f = *(const float4*)(brow + (size_t)w * CC + c4);
            int pp = w & 1;
            int s  = 10 + (w >> 1);
            __bf16* dst = &Blds[(pp * BROWS + s) * PITCH + c4];
            dst[0] = (__bf16)f.x; dst[1] = (__bf16)f.y;
            dst[2] = (__bf16)f.z; dst[3] = (__bf16)f.w;
        }
        __syncthreads();

        v4f acc0 = {0.f, 0.f, 0.f, 0.f};
        v4f acc1 = acc0, acc2 = acc0;
        const __bf16* bbase = &Blds[(p * BROWS + n) * PITCH + quad * 8];
        #pragma unroll
        for (int kc = 0; kc < 8; ++kc) {
            int ko = kc * 32;
            v8bf16 b0 = *(const v8bf16*)(bbase + s0_0 * PITCH + ko);
            v8bf16 b1 = *(const v8bf16*)(bbase + s0_1 * PITCH + ko);
            v8bf16 b2 = *(const v8bf16*)(bbase + s0_2 * PITCH + ko);
            acc0 = __builtin_amdgcn_mfma_f32_16x16x32_bf16(afrag[kc], b0, acc0, 0, 0, 0);
            acc1 = __builtin_amdgcn_mfma_f32_16x16x32_bf16(afrag[kc], b1, acc1, 0, 0, 0);
            acc2 = __builtin_amdgcn_mfma_f32_16x16x32_bf16(afrag[kc], b2, acc2, 0, 0, 0);
        }

        // epilogue: D layout col = lane&15 (-> s), row = quad*4 + r (-> w' within tile)
        #pragma unroll
        for (int jt = 0; jt < 3; ++jt) {
            v4f acc = (jt == 0) ? acc0 : ((jt == 1) ? acc1 : acc2);
            int s0  = (jt == 0) ? s0_0 : ((jt == 1) ? s0_1 : s0_2);
            int s   = s0 + n;
            bool nok = (mt == 0) || (jt != 0) || (n < 14);   // dedup overlap rows s in {20,21}
            #pragma unroll
            for (int r = 0; r < 4; ++r) {
                int m  = quad * 4 + r;
                int wp = mt * 16 + m;            // w'
                int ti = s - wp;
                if (nok && (unsigned)ti < 21u) {
                    int w = (wp << 1) + p;
                    outbh[(size_t)w * OUTD + tj * ND + ti] = acc[r] * (1.f / 256.f);
                }
            }
        }
    }
}

extern "C" void kernel_launch(void* const* d_in, const int* in_sizes, int n_in,
                              void* d_out, int out_size, void* d_ws, size_t ws_size,
                              hipStream_t stream) {
    const float* A = (const float*)d_in[0];
    const float* B = (const float*)d_in[1];
    float* out = (float*)d_out;
    dim3 grid(BATCH * HH);
    dim3 block(256);
    corr_mfma_kernel<<<grid, block, 0, stream>>>(A, B, out);
}